// Round 18
// baseline (112.503 us; speedup 1.0000x reference)
//
#include <hip/hip_runtime.h>
#include <hip/hip_bf16.h>

// MHA forward: B=2, S=2048, D=1024, H=16, depth=64.
// All GEMMs in bf16 MFMA (16x16x32), fp32 accumulation.

typedef __bf16 bf16x8 __attribute__((ext_vector_type(8)));
typedef float f32x4 __attribute__((ext_vector_type(4)));
typedef unsigned short u16;
typedef unsigned short u16x4 __attribute__((ext_vector_type(4)));
typedef unsigned short u16x8 __attribute__((ext_vector_type(8)));
typedef unsigned int u32x2 __attribute__((ext_vector_type(2)));

__device__ __forceinline__ u16 f2bf(float f) {
  union { float f; unsigned u; } x; x.f = f;
  return (u16)((x.u + 0x7fffu + ((x.u >> 16) & 1u)) >> 16);   // RNE
}

// async global->LDS, 16B per lane. LDS dest is wave-uniform base (+lane*16 in HW).
__device__ __forceinline__ void load_lds16(const void* g, void* l) {
  __builtin_amdgcn_global_load_lds((const __attribute__((address_space(1))) void*)g,
                                   (__attribute__((address_space(3))) void*)l,
                                   16, 0, 0);
}

// LDS tile readers. Rows XOR-swizzled with ((row&7)<<4) to kill the
// 16-way bank conflict of 128B/256B-stride row-major reads (G4).
__device__ __forceinline__ bf16x8 frag128(const u16* base, int row, int ch) {
  return *(const bf16x8*)((const char*)base + row * 128 + (((ch) ^ (row & 7)) << 4));
}

// hardware 2^x (1 VALU op; log2e is pre-folded into Q)
__device__ __forceinline__ float exp2_hw(float x) {
  float r;
  asm("v_exp_f32 %0, %1" : "=v"(r) : "v"(x));
  return r;
}

// pack 2 f32 -> 2 bf16 in one u32 (lo = first operand), RNE. No builtin (m240).
__device__ __forceinline__ unsigned cvt_pk_bf16(float lo, float hi) {
  unsigned r;
  asm("v_cvt_pk_bf16_f32 %0, %1, %2" : "=v"(r) : "v"(lo), "v"(hi));
  return r;
}

// assemble a bf16x8 MFMA operand from 4 u32s (each = 2 packed bf16)
__device__ __forceinline__ bf16x8 mk8(unsigned a, unsigned b, unsigned c,
                                      unsigned d) {
  union { unsigned u[4]; bf16x8 v; } x;
  x.u[0] = a; x.u[1] = b; x.u[2] = c; x.u[3] = d;
  return x.v;
}

// ---------------------------------------------------------------- convert
// One launch for all 5 fp32->bf16 conversions. dst is contiguous in ws:
// x16 (1048576 vec4) then wq,wk,wv,wo (262144 vec4 each).
__global__ __launch_bounds__(256) void cvt_all(
    const float* __restrict__ x, const float* __restrict__ wq,
    const float* __restrict__ wk, const float* __restrict__ wv,
    const float* __restrict__ wo, u16* __restrict__ dst) {
  int i = blockIdx.x * 256 + threadIdx.x;  // u16x4 index, 2097152 total
  const float* src;
  int loc;
  if (i < 1048576) {
    src = x; loc = i;
  } else {
    int j = i - 1048576;
    int seg = j >> 18;
    loc = j & 262143;
    src = (seg == 0) ? wq : (seg == 1) ? wk : (seg == 2) ? wv : wo;
  }
  f32x4 v = ((const f32x4*)src)[loc];
  u16x4 o;
#pragma unroll
  for (int j = 0; j < 4; ++j) o[j] = f2bf(v[j]);
  ((u16x4*)dst)[i] = o;
}

// ---------------------------------------------------------------- GEMM
// C[M,N] = A[M,K] @ Bw[N,K]^T (+bias). BMx128 tile, 4 waves (2x2),
// wave tile (BM/2)x64. XCD-bijective block swizzle (T1) for L2 panel reuse.
// MODE 0: QKV epilogue -> bf16; Q scaled log2e/8; V^T to vt[bh][d][*] with
// the pi k-permutation baked in (pos = 32g + 8lq + 4u + r for
// s = 32g + 16u + 4lq + r) so attention's PV B-frag is ONE b128 per group.
// MODE 1: fp32 out + bias.
template <int BM, int MODE>
__global__ __launch_bounds__(256) void gemm_bf16(
    const u16* __restrict__ A, const u16* __restrict__ Bw,
    const float* __restrict__ bias0, const float* __restrict__ bias1,
    const float* __restrict__ bias2,
    u16* __restrict__ o_q, u16* __restrict__ o_k, u16* __restrict__ o_vt,
    float* __restrict__ o_f, int K) {
  constexpr int MBF = BM / 32;           // M-frags per wave
  constexpr int NBX = (MODE == 0) ? 24 : 8;
  constexpr int NBY = 4096 / BM;
  __shared__ u16 sA[BM * 64];
  __shared__ u16 sB[128 * 64];
  const int tid = threadIdx.x, l = tid & 63, w = tid >> 6;
  const int wr = w >> 1, wc = w & 1;
  const int lr = l & 15, lq = l >> 4;
  // XCD swizzle: nwg % 8 == 0 for both grids
  const int lin = blockIdx.y * NBX + blockIdx.x;
  const int wgs = (lin & 7) * (NBX * NBY / 8) + (lin >> 3);
  const int m0 = (wgs / NBX) * BM, n0 = (wgs % NBX) * 128;

  f32x4 acc[MBF][4];
#pragma unroll
  for (int mb = 0; mb < MBF; ++mb)
#pragma unroll
    for (int nb = 0; nb < 4; ++nb) acc[mb][nb] = f32x4{0.f, 0.f, 0.f, 0.f};

  const int nkt = K / 64;
  for (int kt = 0; kt < nkt; ++kt) {
#pragma unroll
    for (int i = 0; i < BM / 32; ++i) {
      int p = (i * 4 + w) * 1024 + l * 16;
      int row = p >> 7, ch = ((p >> 4) & 7) ^ (row & 7);
      load_lds16(A + (size_t)(m0 + row) * K + kt * 64 + ch * 8,
                 (char*)sA + (i * 4 + w) * 1024);
    }
#pragma unroll
    for (int i = 0; i < 4; ++i) {
      int p = (i * 4 + w) * 1024 + l * 16;
      int row = p >> 7, ch = ((p >> 4) & 7) ^ (row & 7);
      load_lds16(Bw + (size_t)(n0 + row) * K + kt * 64 + ch * 8,
                 (char*)sB + (i * 4 + w) * 1024);
    }
    __syncthreads();
#pragma unroll
    for (int ks = 0; ks < 2; ++ks) {
      bf16x8 af[MBF], bfr[4];
#pragma unroll
      for (int mb = 0; mb < MBF; ++mb)
        af[mb] = frag128(sA, wr * (BM / 2) + mb * 16 + lr, lq + 4 * ks);
#pragma unroll
      for (int nb = 0; nb < 4; ++nb)
        bfr[nb] = frag128(sB, wc * 64 + nb * 16 + lr, lq + 4 * ks);
#pragma unroll
      for (int mb = 0; mb < MBF; ++mb)
#pragma unroll
        for (int nb = 0; nb < 4; ++nb)
          acc[mb][nb] = __builtin_amdgcn_mfma_f32_16x16x32_bf16(
              af[mb], bfr[nb], acc[mb][nb], 0, 0, 0);
    }
    __syncthreads();
  }

  // epilogue. C/D layout: col = lane&15, row = (lane>>4)*4 + reg  [m89/m91].
#pragma unroll
  for (int nb = 0; nb < 4; ++nb) {
    const int n = n0 + wc * 64 + nb * 16 + lr;
    if constexpr (MODE == 0) {
      const int qkv = n >> 10, c = n & 1023;
      const float* bp = (qkv == 0) ? bias0 : ((qkv == 1) ? bias1 : bias2);
      const float bv = bp[c];
      const int h = c >> 6, d = c & 63;
      if (qkv == 2) {
        // V transposed + pi-permuted within each 32-s group:
        // s = 32g+16u+4l'+r -> pos = 32g+8l'+4u+r (4 consecutive r packed).
#pragma unroll
        for (int mb = 0; mb < MBF; ++mb) {
          int mbase = m0 + wr * (BM / 2) + mb * 16 + lq * 4;
          int b = mbase >> 11, s0 = mbase & 2047;
          int pos0 = (s0 & ~31) | (((s0 >> 2) & 3) << 3) | (((s0 >> 4) & 1) << 2);
          u16x4 pk;
#pragma unroll
          for (int r = 0; r < 4; ++r) pk[r] = f2bf(acc[mb][nb][r] + bv);
          *(u16x4*)(o_vt + ((size_t)((b * 16 + h) * 64 + d)) * 2048 + pos0) = pk;
        }
      } else {
        u16* dp = (qkv == 0) ? o_q : o_k;
#pragma unroll
        for (int mb = 0; mb < MBF; ++mb)
#pragma unroll
          for (int r = 0; r < 4; ++r) {
            int m = m0 + wr * (BM / 2) + mb * 16 + lq * 4 + r;
            int b = m >> 11, s = m & 2047;
            float v = acc[mb][nb][r] + bv;
            if (qkv == 0) v *= 0.18033688011f;  // (1/8)*log2(e)
            dp[((size_t)(b * 16 + h) * 2048 + s) * 64 + d] = f2bf(v);
          }
      }
    } else {
      const float bv = bias0[n];
#pragma unroll
      for (int mb = 0; mb < MBF; ++mb)
#pragma unroll
        for (int r = 0; r < 4; ++r) {
          int m = m0 + wr * (BM / 2) + mb * 16 + lq * 4 + r;
          o_f[(size_t)m * 1024 + n] = acc[mb][nb][r] + bv;
        }
    }
  }
}

// ---------------------------------------------------------------- attention
// grid (16 q-tiles of 128, 32 bh) = 512 blocks, 2 blocks/CU. 4 waves; wave w
// owns 32 q-rows as mb=0,1. K/V tiles of 128. XCD-bijective block swizzle.
// Round-14 verified structure: DMA staging (pre-swizzled global source,
// linear LDS dest), double-buffered K/V, one barrier per tile; swapped QK^T
// (q on cols, k lane-local); m=0 softmax (|S|<=~3, exact; Q pre-scaled
// log2e/8 -> exp2 direct); P stays in registers via the pi k-permutation;
// V pi-permuted in memory so each PV B-frag is one ds_read_b128.
// NOTE: r12/r15 (cross-tile P pipeline) spilled; r16 (MFMA||MFMA split)
// neutral; r17 (MFMA||VALU interleave) NaN'd — this serial-per-tile form is
// the verified optimum of this structure family.
__global__ __launch_bounds__(256, 2) void attn_fwd(
    const u16* __restrict__ q16, const u16* __restrict__ k16,
    const u16* __restrict__ vt16, u16* __restrict__ att16) {
  __shared__ u16 sK[2][128 * 64];  // [128 k][64 d], swizzled 128B rows
  __shared__ u16 sV[2][64 * 128];  // [64 d][128 k-pos], swizzled 256B rows
  const int tid = threadIdx.x, l = tid & 63, w = tid >> 6;
  const int lr = l & 15, lq = l >> 4;
  const int lin = (blockIdx.y << 4) | blockIdx.x;
  const int wg = (lin & 7) * 64 + (lin >> 3);   // bijective XCD chunking
  const int qt = wg & 15, bh = wg >> 4;
  const int b = bh >> 4, h = bh & 15;
  const char* kg = (const char*)(k16 + (size_t)bh * 2048 * 64);
  const char* vg = (const char*)(vt16 + (size_t)bh * 64 * 2048);

  // Q B-fragments in registers (col q = lane&15 within mb-block).
  bf16x8 aq[2][2];
#pragma unroll
  for (int mb = 0; mb < 2; ++mb)
#pragma unroll
    for (int ks = 0; ks < 2; ++ks) {
      int qrow = qt * 128 + w * 32 + mb * 16 + lr;
      aq[mb][ks] = *(const bf16x8*)(q16 + ((size_t)bh * 2048 + qrow) * 64 +
                                    ks * 32 + lq * 8);
    }

  // DMA source offsets (pre-swizzled so linear LDS dest = swizzled layout).
  int koff[4], voff[4];
#pragma unroll
  for (int i = 0; i < 4; ++i) {
    int p = (i * 4 + w) * 1024 + l * 16;
    int krow = p >> 7, kch = ((p >> 4) & 7) ^ (krow & 7);
    koff[i] = krow * 128 + kch * 16;               // byte off within K tile
    int vrow = p >> 8, vch = ((p >> 4) & 15) ^ (vrow & 7);
    voff[i] = vrow * 4096 + vch * 16;              // byte off in vt (row=4096B)
  }

  // prologue: DMA tile 0 into buf 0
#pragma unroll
  for (int i = 0; i < 4; ++i)
    load_lds16(kg + koff[i], (char*)sK[0] + (i * 4 + w) * 1024);
#pragma unroll
  for (int i = 0; i < 4; ++i)
    load_lds16(vg + voff[i], (char*)sV[0] + (i * 4 + w) * 1024);
  __syncthreads();

  f32x4 o[2][4];
#pragma unroll
  for (int mb = 0; mb < 2; ++mb)
#pragma unroll
    for (int db = 0; db < 4; ++db) o[mb][db] = f32x4{0.f, 0.f, 0.f, 0.f};
  float l_run[2] = {0.f, 0.f};

  for (int kt = 0; kt < 16; ++kt) {
    const int cur = kt & 1;
    const u16* sKc = sK[cur];
    const u16* sVc = sV[cur];

    // issue DMA for tile kt+1 into the other buffer (covers whole body)
    if (kt < 15) {
      char* dK = (char*)sK[cur ^ 1];
      char* dV = (char*)sV[cur ^ 1];
#pragma unroll
      for (int i = 0; i < 4; ++i)
        load_lds16(kg + (size_t)(kt + 1) * 16384 + koff[i],
                   dK + (i * 4 + w) * 1024);
#pragma unroll
      for (int i = 0; i < 4; ++i)
        load_lds16(vg + (size_t)(kt + 1) * 256 + voff[i],
                   dV + (i * 4 + w) * 1024);
    }

    // S^T = K Q^T (swapped): lane holds q = lr (per mb), k = 16nb + 4lq + r
    f32x4 s[2][8];
#pragma unroll
    for (int mb = 0; mb < 2; ++mb)
#pragma unroll
      for (int nb = 0; nb < 8; ++nb) s[mb][nb] = f32x4{0.f, 0.f, 0.f, 0.f};
    __builtin_amdgcn_s_setprio(1);
#pragma unroll
    for (int ks = 0; ks < 2; ++ks) {
#pragma unroll
      for (int g = 0; g < 2; ++g) {
        bf16x8 bk[4];
#pragma unroll
        for (int j = 0; j < 4; ++j)
          bk[j] = frag128(sKc, (g * 4 + j) * 16 + lr, lq + 4 * ks);
#pragma unroll
        for (int j = 0; j < 4; ++j)
#pragma unroll
          for (int mb = 0; mb < 2; ++mb)   // one bk read feeds 2 MFMAs
            s[mb][g * 4 + j] = __builtin_amdgcn_mfma_f32_16x16x32_bf16(
                bk[j], aq[mb][ks], s[mb][g * 4 + j], 0, 0, 0);
      }
    }
    __builtin_amdgcn_s_setprio(0);

    // softmax m=0: P = 2^S, per-lane scalar partial row-sum per mb (q = lr)
#pragma unroll
    for (int mb = 0; mb < 2; ++mb) {
      float rs = 0.f;
#pragma unroll
      for (int nb = 0; nb < 8; ++nb)
#pragma unroll
        for (int r = 0; r < 4; ++r) {
          float p_ = exp2_hw(s[mb][nb][r]);
          s[mb][nb][r] = p_;
          rs += p_;
        }
      l_run[mb] += rs;
    }

    // PV, k-groups g=0..3 under pi: A-frag = cvt_pk of s[2g],s[2g+1]
    // (registers); B-frag = ONE ds_read_b128 (V pi-permuted in memory).
#pragma unroll
    for (int g = 0; g < 4; ++g) {
      bf16x8 ap[2];
#pragma unroll
      for (int mb = 0; mb < 2; ++mb)
        ap[mb] = mk8(cvt_pk_bf16(s[mb][2 * g][0], s[mb][2 * g][1]),
                     cvt_pk_bf16(s[mb][2 * g][2], s[mb][2 * g][3]),
                     cvt_pk_bf16(s[mb][2 * g + 1][0], s[mb][2 * g + 1][1]),
                     cvt_pk_bf16(s[mb][2 * g + 1][2], s[mb][2 * g + 1][3]));
      bf16x8 bv[4];
#pragma unroll
      for (int db = 0; db < 4; ++db) {
        int row = db * 16 + lr;
        bv[db] = *(const bf16x8*)((const char*)sVc + row * 256 +
                                  (((4 * g + lq) ^ (row & 7)) << 4));
      }
      __builtin_amdgcn_s_setprio(1);
#pragma unroll
      for (int db = 0; db < 4; ++db)
#pragma unroll
        for (int mb = 0; mb < 2; ++mb)  // one bv read feeds 2 MFMAs
          o[mb][db] = __builtin_amdgcn_mfma_f32_16x16x32_bf16(
              ap[mb], bv[db], o[mb][db], 0, 0, 0);
      __builtin_amdgcn_s_setprio(0);
    }

    __syncthreads();  // drains DMA (vmcnt 0) + fences buffer reuse
  }

  // epilogue: l lives per-lane (q = lr, per mb); reduce across lq groups,
  // then redistribute to the o layout (q = mb*16 + lq*4 + r).
#pragma unroll
  for (int mb = 0; mb < 2; ++mb) {
    float lv = l_run[mb];
    lv += __shfl_xor(lv, 16, 64);
    lv += __shfl_xor(lv, 32, 64);
    float inv[4];
#pragma unroll
    for (int r = 0; r < 4; ++r) inv[r] = 1.f / __shfl(lv, lq * 4 + r, 64);
#pragma unroll
    for (int db = 0; db < 4; ++db)
#pragma unroll
      for (int r = 0; r < 4; ++r) {
        float v = o[mb][db][r] * inv[r];
        int qg_ = qt * 128 + w * 32 + mb * 16 + lq * 4 + r;
        int col = h * 64 + db * 16 + lr;
        att16[((size_t)(b * 2048 + qg_)) * 1024 + col] = f2bf(v);
      }
  }
}

// ---------------------------------------------------------------- launch
extern "C" void kernel_launch(void* const* d_in, const int* in_sizes, int n_in,
                              void* d_out, int out_size, void* d_ws, size_t ws_size,
                              hipStream_t stream) {
  const float* x  = (const float*)d_in[0];
  const float* Wq = (const float*)d_in[1];
  const float* bq = (const float*)d_in[2];
  const float* Wk = (const float*)d_in[3];
  const float* bk = (const float*)d_in[4];
  const float* Wv = (const float*)d_in[5];
  const float* bv = (const float*)d_in[6];
  const float* Wo = (const float*)d_in[7];
  const float* bo = (const float*)d_in[8];
  float* out = (float*)d_out;

  char* ws = (char*)d_ws;
  const size_t MB = 1024 * 1024;
  if (ws_size < 40 * MB) return;  // need 40 MiB scratch
  u16* x16  = (u16*)(ws);             // 8 MiB; reused as att16 after QKV GEMM
  u16* w16  = (u16*)(ws + 8 * MB);    // 8 MiB: Wq,Wk,Wv,Wo bf16
  u16* q16  = (u16*)(ws + 16 * MB);   // 8 MiB [bh][s][64], scaled log2e/8
  u16* k16  = (u16*)(ws + 24 * MB);   // 8 MiB [bh][s][64]
  u16* vt16 = (u16*)(ws + 32 * MB);   // 8 MiB [bh][64][pos] pi-permuted
  u16* att16 = x16;

  // fp32 -> bf16, one launch (dst = x16 ++ w16, contiguous)
  cvt_all<<<8192, 256, 0, stream>>>(x, Wq, Wk, Wv, Wo, x16);

  // fused QKV projection: [4096,1024] @ [3072,1024]^T; V written transposed
  gemm_bf16<128, 0><<<dim3(24, 32), 256, 0, stream>>>(
      x16, w16, bq, bk, bv, q16, k16, vt16, nullptr, 1024);

  // flash attention
  attn_fwd<<<dim3(16, 32), 256, 0, stream>>>(q16, k16, vt16, att16);

  // out projection: [4096,1024] @ [1024,1024]^T + bo -> fp32, BM=128 tile
  // (BM=128 staging/compute path is the QKV-verified one; MODE-1 epilogue
  // is BM-agnostic). Grid 8x32 = 256 blocks, swizzle stays bijective.
  gemm_bf16<128, 1><<<dim3(8, 32), 256, 0, stream>>>(
      att16, w16 + 3145728, bo, nullptr, nullptr, nullptr, nullptr, nullptr,
      out, 1024);
}

// Round 19
// 106.408 us; speedup vs baseline: 1.0573x; 1.0573x over previous
//
#include <hip/hip_runtime.h>
#include <hip/hip_bf16.h>

// MHA forward: B=2, S=2048, D=1024, H=16, depth=64.
// All GEMMs in bf16 MFMA (16x16x32), fp32 accumulation.

typedef __bf16 bf16x8 __attribute__((ext_vector_type(8)));
typedef float f32x4 __attribute__((ext_vector_type(4)));
typedef unsigned short u16;
typedef unsigned short u16x4 __attribute__((ext_vector_type(4)));
typedef unsigned short u16x8 __attribute__((ext_vector_type(8)));
typedef unsigned int u32x2 __attribute__((ext_vector_type(2)));

__device__ __forceinline__ u16 f2bf(float f) {
  union { float f; unsigned u; } x; x.f = f;
  return (u16)((x.u + 0x7fffu + ((x.u >> 16) & 1u)) >> 16);   // RNE
}

// async global->LDS, 16B per lane. LDS dest is wave-uniform base (+lane*16 in HW).
__device__ __forceinline__ void load_lds16(const void* g, void* l) {
  __builtin_amdgcn_global_load_lds((const __attribute__((address_space(1))) void*)g,
                                   (__attribute__((address_space(3))) void*)l,
                                   16, 0, 0);
}

// LDS tile readers. Rows XOR-swizzled with ((row&7)<<4) to kill the
// 16-way bank conflict of 128B/256B-stride row-major reads (G4).
__device__ __forceinline__ bf16x8 frag128(const u16* base, int row, int ch) {
  return *(const bf16x8*)((const char*)base + row * 128 + (((ch) ^ (row & 7)) << 4));
}

// hardware 2^x (1 VALU op; log2e is pre-folded into Q)
__device__ __forceinline__ float exp2_hw(float x) {
  float r;
  asm("v_exp_f32 %0, %1" : "=v"(r) : "v"(x));
  return r;
}

// pack 2 f32 -> 2 bf16 in one u32 (lo = first operand), RNE. No builtin (m240).
__device__ __forceinline__ unsigned cvt_pk_bf16(float lo, float hi) {
  unsigned r;
  asm("v_cvt_pk_bf16_f32 %0, %1, %2" : "=v"(r) : "v"(lo), "v"(hi));
  return r;
}

// assemble a bf16x8 MFMA operand from 4 u32s (each = 2 packed bf16)
__device__ __forceinline__ bf16x8 mk8(unsigned a, unsigned b, unsigned c,
                                      unsigned d) {
  union { unsigned u[4]; bf16x8 v; } x;
  x.u[0] = a; x.u[1] = b; x.u[2] = c; x.u[3] = d;
  return x.v;
}

// ---------------------------------------------------------------- convert
// One launch for all 5 fp32->bf16 conversions. dst is contiguous in ws:
// x16 (1048576 vec4) then wq,wk,wv,wo (262144 vec4 each).
__global__ __launch_bounds__(256) void cvt_all(
    const float* __restrict__ x, const float* __restrict__ wq,
    const float* __restrict__ wk, const float* __restrict__ wv,
    const float* __restrict__ wo, u16* __restrict__ dst) {
  int i = blockIdx.x * 256 + threadIdx.x;  // u16x4 index, 2097152 total
  const float* src;
  int loc;
  if (i < 1048576) {
    src = x; loc = i;
  } else {
    int j = i - 1048576;
    int seg = j >> 18;
    loc = j & 262143;
    src = (seg == 0) ? wq : (seg == 1) ? wk : (seg == 2) ? wv : wo;
  }
  f32x4 v = ((const f32x4*)src)[loc];
  u16x4 o;
#pragma unroll
  for (int j = 0; j < 4; ++j) o[j] = f2bf(v[j]);
  ((u16x4*)dst)[i] = o;
}

// ---------------------------------------------------------------- GEMM
// C[M,N] = A[M,K] @ Bw[N,K]^T (+bias). BMx128 tile, 4 waves (2x2),
// wave tile (BM/2)x64. XCD-bijective block swizzle (T1) for L2 panel reuse.
// MODE 0: QKV epilogue -> bf16; Q scaled log2e/8; V^T to vt[bh][d][*] with
// the pi k-permutation baked in (pos = 32g + 8lq + 4u + r for
// s = 32g + 16u + 4lq + r) so attention's PV B-frag is ONE b128 per group.
// MODE 1: fp32 out + bias.
template <int BM, int MODE>
__global__ __launch_bounds__(256) void gemm_bf16(
    const u16* __restrict__ A, const u16* __restrict__ Bw,
    const float* __restrict__ bias0, const float* __restrict__ bias1,
    const float* __restrict__ bias2,
    u16* __restrict__ o_q, u16* __restrict__ o_k, u16* __restrict__ o_vt,
    float* __restrict__ o_f, int K) {
  constexpr int MBF = BM / 32;           // M-frags per wave
  constexpr int NBX = (MODE == 0) ? 24 : 8;
  constexpr int NBY = 4096 / BM;
  __shared__ u16 sA[BM * 64];
  __shared__ u16 sB[128 * 64];
  const int tid = threadIdx.x, l = tid & 63, w = tid >> 6;
  const int wr = w >> 1, wc = w & 1;
  const int lr = l & 15, lq = l >> 4;
  // XCD swizzle: nwg % 8 == 0 for both grids
  const int lin = blockIdx.y * NBX + blockIdx.x;
  const int wgs = (lin & 7) * (NBX * NBY / 8) + (lin >> 3);
  const int m0 = (wgs / NBX) * BM, n0 = (wgs % NBX) * 128;

  f32x4 acc[MBF][4];
#pragma unroll
  for (int mb = 0; mb < MBF; ++mb)
#pragma unroll
    for (int nb = 0; nb < 4; ++nb) acc[mb][nb] = f32x4{0.f, 0.f, 0.f, 0.f};

  const int nkt = K / 64;
  for (int kt = 0; kt < nkt; ++kt) {
#pragma unroll
    for (int i = 0; i < BM / 32; ++i) {
      int p = (i * 4 + w) * 1024 + l * 16;
      int row = p >> 7, ch = ((p >> 4) & 7) ^ (row & 7);
      load_lds16(A + (size_t)(m0 + row) * K + kt * 64 + ch * 8,
                 (char*)sA + (i * 4 + w) * 1024);
    }
#pragma unroll
    for (int i = 0; i < 4; ++i) {
      int p = (i * 4 + w) * 1024 + l * 16;
      int row = p >> 7, ch = ((p >> 4) & 7) ^ (row & 7);
      load_lds16(Bw + (size_t)(n0 + row) * K + kt * 64 + ch * 8,
                 (char*)sB + (i * 4 + w) * 1024);
    }
    __syncthreads();
#pragma unroll
    for (int ks = 0; ks < 2; ++ks) {
      bf16x8 af[MBF], bfr[4];
#pragma unroll
      for (int mb = 0; mb < MBF; ++mb)
        af[mb] = frag128(sA, wr * (BM / 2) + mb * 16 + lr, lq + 4 * ks);
#pragma unroll
      for (int nb = 0; nb < 4; ++nb)
        bfr[nb] = frag128(sB, wc * 64 + nb * 16 + lr, lq + 4 * ks);
#pragma unroll
      for (int mb = 0; mb < MBF; ++mb)
#pragma unroll
        for (int nb = 0; nb < 4; ++nb)
          acc[mb][nb] = __builtin_amdgcn_mfma_f32_16x16x32_bf16(
              af[mb], bfr[nb], acc[mb][nb], 0, 0, 0);
    }
    __syncthreads();
  }

  // epilogue. C/D layout: col = lane&15, row = (lane>>4)*4 + reg  [m89/m91].
#pragma unroll
  for (int nb = 0; nb < 4; ++nb) {
    const int n = n0 + wc * 64 + nb * 16 + lr;
    if constexpr (MODE == 0) {
      const int qkv = n >> 10, c = n & 1023;
      const float* bp = (qkv == 0) ? bias0 : ((qkv == 1) ? bias1 : bias2);
      const float bv = bp[c];
      const int h = c >> 6, d = c & 63;
      if (qkv == 2) {
        // V transposed + pi-permuted within each 32-s group:
        // s = 32g+16u+4l'+r -> pos = 32g+8l'+4u+r (4 consecutive r packed).
#pragma unroll
        for (int mb = 0; mb < MBF; ++mb) {
          int mbase = m0 + wr * (BM / 2) + mb * 16 + lq * 4;
          int b = mbase >> 11, s0 = mbase & 2047;
          int pos0 = (s0 & ~31) | (((s0 >> 2) & 3) << 3) | (((s0 >> 4) & 1) << 2);
          u16x4 pk;
#pragma unroll
          for (int r = 0; r < 4; ++r) pk[r] = f2bf(acc[mb][nb][r] + bv);
          *(u16x4*)(o_vt + ((size_t)((b * 16 + h) * 64 + d)) * 2048 + pos0) = pk;
        }
      } else {
        u16* dp = (qkv == 0) ? o_q : o_k;
#pragma unroll
        for (int mb = 0; mb < MBF; ++mb)
#pragma unroll
          for (int r = 0; r < 4; ++r) {
            int m = m0 + wr * (BM / 2) + mb * 16 + lq * 4 + r;
            int b = m >> 11, s = m & 2047;
            float v = acc[mb][nb][r] + bv;
            if (qkv == 0) v *= 0.18033688011f;  // (1/8)*log2(e)
            dp[((size_t)(b * 16 + h) * 2048 + s) * 64 + d] = f2bf(v);
          }
      }
    } else {
      const float bv = bias0[n];
#pragma unroll
      for (int mb = 0; mb < MBF; ++mb)
#pragma unroll
        for (int r = 0; r < 4; ++r) {
          int m = m0 + wr * (BM / 2) + mb * 16 + lq * 4 + r;
          o_f[(size_t)m * 1024 + n] = acc[mb][nb][r] + bv;
        }
    }
  }
}

// ---------------------------------------------------------------- attention
// grid (16 q-tiles of 128, 32 bh) = 512 blocks, 2 blocks/CU. 4 waves; wave w
// owns 32 q-rows as mb=0,1. K/V tiles of 128. XCD-bijective block swizzle.
// Round-14 verified structure: DMA staging (pre-swizzled global source,
// linear LDS dest), double-buffered K/V, one barrier per tile; swapped QK^T
// (q on cols, k lane-local); m=0 softmax (|S|<=~3, exact; Q pre-scaled
// log2e/8 -> exp2 direct); P stays in registers via the pi k-permutation;
// V pi-permuted in memory so each PV B-frag is one ds_read_b128.
// NOTE: r12/r15 (cross-tile P pipeline) spilled; r16 (MFMA||MFMA split)
// neutral; r17 (MFMA||VALU interleave) NaN'd — this serial-per-tile form is
// the verified optimum of this structure family.
__global__ __launch_bounds__(256, 2) void attn_fwd(
    const u16* __restrict__ q16, const u16* __restrict__ k16,
    const u16* __restrict__ vt16, u16* __restrict__ att16) {
  __shared__ u16 sK[2][128 * 64];  // [128 k][64 d], swizzled 128B rows
  __shared__ u16 sV[2][64 * 128];  // [64 d][128 k-pos], swizzled 256B rows
  const int tid = threadIdx.x, l = tid & 63, w = tid >> 6;
  const int lr = l & 15, lq = l >> 4;
  const int lin = (blockIdx.y << 4) | blockIdx.x;
  const int wg = (lin & 7) * 64 + (lin >> 3);   // bijective XCD chunking
  const int qt = wg & 15, bh = wg >> 4;
  const int b = bh >> 4, h = bh & 15;
  const char* kg = (const char*)(k16 + (size_t)bh * 2048 * 64);
  const char* vg = (const char*)(vt16 + (size_t)bh * 64 * 2048);

  // Q B-fragments in registers (col q = lane&15 within mb-block).
  bf16x8 aq[2][2];
#pragma unroll
  for (int mb = 0; mb < 2; ++mb)
#pragma unroll
    for (int ks = 0; ks < 2; ++ks) {
      int qrow = qt * 128 + w * 32 + mb * 16 + lr;
      aq[mb][ks] = *(const bf16x8*)(q16 + ((size_t)bh * 2048 + qrow) * 64 +
                                    ks * 32 + lq * 8);
    }

  // DMA source offsets (pre-swizzled so linear LDS dest = swizzled layout).
  int koff[4], voff[4];
#pragma unroll
  for (int i = 0; i < 4; ++i) {
    int p = (i * 4 + w) * 1024 + l * 16;
    int krow = p >> 7, kch = ((p >> 4) & 7) ^ (krow & 7);
    koff[i] = krow * 128 + kch * 16;               // byte off within K tile
    int vrow = p >> 8, vch = ((p >> 4) & 15) ^ (vrow & 7);
    voff[i] = vrow * 4096 + vch * 16;              // byte off in vt (row=4096B)
  }

  // prologue: DMA tile 0 into buf 0
#pragma unroll
  for (int i = 0; i < 4; ++i)
    load_lds16(kg + koff[i], (char*)sK[0] + (i * 4 + w) * 1024);
#pragma unroll
  for (int i = 0; i < 4; ++i)
    load_lds16(vg + voff[i], (char*)sV[0] + (i * 4 + w) * 1024);
  __syncthreads();

  f32x4 o[2][4];
#pragma unroll
  for (int mb = 0; mb < 2; ++mb)
#pragma unroll
    for (int db = 0; db < 4; ++db) o[mb][db] = f32x4{0.f, 0.f, 0.f, 0.f};
  float l_run[2] = {0.f, 0.f};

  for (int kt = 0; kt < 16; ++kt) {
    const int cur = kt & 1;
    const u16* sKc = sK[cur];
    const u16* sVc = sV[cur];

    // issue DMA for tile kt+1 into the other buffer (covers whole body)
    if (kt < 15) {
      char* dK = (char*)sK[cur ^ 1];
      char* dV = (char*)sV[cur ^ 1];
#pragma unroll
      for (int i = 0; i < 4; ++i)
        load_lds16(kg + (size_t)(kt + 1) * 16384 + koff[i],
                   dK + (i * 4 + w) * 1024);
#pragma unroll
      for (int i = 0; i < 4; ++i)
        load_lds16(vg + (size_t)(kt + 1) * 256 + voff[i],
                   dV + (i * 4 + w) * 1024);
    }

    // S^T = K Q^T (swapped): lane holds q = lr (per mb), k = 16nb + 4lq + r
    f32x4 s[2][8];
#pragma unroll
    for (int mb = 0; mb < 2; ++mb)
#pragma unroll
      for (int nb = 0; nb < 8; ++nb) s[mb][nb] = f32x4{0.f, 0.f, 0.f, 0.f};
    __builtin_amdgcn_s_setprio(1);
#pragma unroll
    for (int ks = 0; ks < 2; ++ks) {
#pragma unroll
      for (int g = 0; g < 2; ++g) {
        bf16x8 bk[4];
#pragma unroll
        for (int j = 0; j < 4; ++j)
          bk[j] = frag128(sKc, (g * 4 + j) * 16 + lr, lq + 4 * ks);
#pragma unroll
        for (int j = 0; j < 4; ++j)
#pragma unroll
          for (int mb = 0; mb < 2; ++mb)   // one bk read feeds 2 MFMAs
            s[mb][g * 4 + j] = __builtin_amdgcn_mfma_f32_16x16x32_bf16(
                bk[j], aq[mb][ks], s[mb][g * 4 + j], 0, 0, 0);
      }
    }
    __builtin_amdgcn_s_setprio(0);

    // softmax m=0: P = 2^S, per-lane scalar partial row-sum per mb (q = lr)
#pragma unroll
    for (int mb = 0; mb < 2; ++mb) {
      float rs = 0.f;
#pragma unroll
      for (int nb = 0; nb < 8; ++nb)
#pragma unroll
        for (int r = 0; r < 4; ++r) {
          float p_ = exp2_hw(s[mb][nb][r]);
          s[mb][nb][r] = p_;
          rs += p_;
        }
      l_run[mb] += rs;
    }

    // PV, k-groups g=0..3 under pi: A-frag = cvt_pk of s[2g],s[2g+1]
    // (registers); B-frag = ONE ds_read_b128 (V pi-permuted in memory).
#pragma unroll
    for (int g = 0; g < 4; ++g) {
      bf16x8 ap[2];
#pragma unroll
      for (int mb = 0; mb < 2; ++mb)
        ap[mb] = mk8(cvt_pk_bf16(s[mb][2 * g][0], s[mb][2 * g][1]),
                     cvt_pk_bf16(s[mb][2 * g][2], s[mb][2 * g][3]),
                     cvt_pk_bf16(s[mb][2 * g + 1][0], s[mb][2 * g + 1][1]),
                     cvt_pk_bf16(s[mb][2 * g + 1][2], s[mb][2 * g + 1][3]));
      bf16x8 bv[4];
#pragma unroll
      for (int db = 0; db < 4; ++db) {
        int row = db * 16 + lr;
        bv[db] = *(const bf16x8*)((const char*)sVc + row * 256 +
                                  (((4 * g + lq) ^ (row & 7)) << 4));
      }
      __builtin_amdgcn_s_setprio(1);
#pragma unroll
      for (int db = 0; db < 4; ++db)
#pragma unroll
        for (int mb = 0; mb < 2; ++mb)  // one bv read feeds 2 MFMAs
          o[mb][db] = __builtin_amdgcn_mfma_f32_16x16x32_bf16(
              ap[mb], bv[db], o[mb][db], 0, 0, 0);
      __builtin_amdgcn_s_setprio(0);
    }

    __syncthreads();  // drains DMA (vmcnt 0) + fences buffer reuse
  }

  // epilogue: l lives per-lane (q = lr, per mb); reduce across lq groups,
  // then redistribute to the o layout (q = mb*16 + lq*4 + r).
#pragma unroll
  for (int mb = 0; mb < 2; ++mb) {
    float lv = l_run[mb];
    lv += __shfl_xor(lv, 16, 64);
    lv += __shfl_xor(lv, 32, 64);
    float inv[4];
#pragma unroll
    for (int r = 0; r < 4; ++r) inv[r] = 1.f / __shfl(lv, lq * 4 + r, 64);
#pragma unroll
    for (int db = 0; db < 4; ++db)
#pragma unroll
      for (int r = 0; r < 4; ++r) {
        float v = o[mb][db][r] * inv[r];
        int qg_ = qt * 128 + w * 32 + mb * 16 + lq * 4 + r;
        int col = h * 64 + db * 16 + lr;
        att16[((size_t)(b * 2048 + qg_)) * 1024 + col] = f2bf(v);
      }
  }
}

// ---------------------------------------------------------------- launch
extern "C" void kernel_launch(void* const* d_in, const int* in_sizes, int n_in,
                              void* d_out, int out_size, void* d_ws, size_t ws_size,
                              hipStream_t stream) {
  const float* x  = (const float*)d_in[0];
  const float* Wq = (const float*)d_in[1];
  const float* bq = (const float*)d_in[2];
  const float* Wk = (const float*)d_in[3];
  const float* bk = (const float*)d_in[4];
  const float* Wv = (const float*)d_in[5];
  const float* bv = (const float*)d_in[6];
  const float* Wo = (const float*)d_in[7];
  const float* bo = (const float*)d_in[8];
  float* out = (float*)d_out;

  char* ws = (char*)d_ws;
  const size_t MB = 1024 * 1024;
  if (ws_size < 40 * MB) return;  // need 40 MiB scratch
  u16* x16  = (u16*)(ws);             // 8 MiB; reused as att16 after QKV GEMM
  u16* w16  = (u16*)(ws + 8 * MB);    // 8 MiB: Wq,Wk,Wv,Wo bf16
  u16* q16  = (u16*)(ws + 16 * MB);   // 8 MiB [bh][s][64], scaled log2e/8
  u16* k16  = (u16*)(ws + 24 * MB);   // 8 MiB [bh][s][64]
  u16* vt16 = (u16*)(ws + 32 * MB);   // 8 MiB [bh][64][pos] pi-permuted
  u16* att16 = x16;

  // fp32 -> bf16, one launch (dst = x16 ++ w16, contiguous)
  cvt_all<<<8192, 256, 0, stream>>>(x, Wq, Wk, Wv, Wo, x16);

  // fused QKV projection: [4096,1024] @ [3072,1024]^T; V written transposed
  gemm_bf16<128, 0><<<dim3(24, 32), 256, 0, stream>>>(
      x16, w16, bq, bk, bv, q16, k16, vt16, nullptr, 1024);

  // flash attention
  attn_fwd<<<dim3(16, 32), 256, 0, stream>>>(q16, k16, vt16, att16);

  // out projection: [4096,1024] @ [1024,1024]^T + bo -> fp32 (BM=64,
  // 512 blocks = 2/CU — BM=128/256-block variant regressed 5us in r18).
  gemm_bf16<64, 1><<<dim3(8, 64), 256, 0, stream>>>(
      att16, w16 + 3145728, bo, nullptr, nullptr, nullptr, nullptr, nullptr,
      out, 1024);
}